// Round 5
// baseline (306.849 us; speedup 1.0000x reference)
//
#include <hip/hip_runtime.h>
#include <math.h>

#define HW 16384
#define IMG 128
#define CDIM 192
#define C3 144
#define C4 48
#define NB 2
#define NPX 32768   // NB*HW
#define HEADS 6

typedef unsigned short u16;
typedef unsigned int u32;
typedef __attribute__((ext_vector_type(8))) short bf16x8;
typedef __attribute__((ext_vector_type(4))) float f32x4;

__device__ __forceinline__ float bf2f(u16 u) {
    return __uint_as_float(((unsigned int)u) << 16);
}
__device__ __forceinline__ u16 f2bf(float f) {
    unsigned int x = __float_as_uint(f);
    unsigned int r = x + 0x7fffu + ((x >> 16) & 1u);  // RNE
    return (u16)(r >> 16);
}

static inline float* wsf(void* ws, size_t off) { return (float*)((char*)ws + off); }
static inline u16* wsh(void* ws, size_t off) { return (u16*)((char*)ws + off); }

// ---------------- K0: setup = weight bf16 conv + tiny GEMVs + tail + S zero --
// wb layout: wq[192][160] | wkv[384][64] | (55296..) unused | wpout @239616 [192][384]
__global__ void k_setup(const float* __restrict__ kvv, const float* __restrict__ wkR,
                        const float* __restrict__ wkI, const float* __restrict__ wffk,
                        const float* __restrict__ wqR, const float* __restrict__ wkvI,
                        const float* __restrict__ wpo, const float* __restrict__ wpin,
                        const float* __restrict__ wpout,
                        u16* __restrict__ wb, float* __restrict__ sm,
                        float* __restrict__ tail) {
    int t = blockIdx.x * 256 + threadIdx.x;
    if (t < 313344) {
        float v;
        if (t < 30720) {
            int o = t / 160, i = t % 160;
            v = (i < 144) ? wqR[o * 144 + i] : 0.f;
        } else if (t < 55296) {
            int r = t - 30720; int o = r / 64, i = r % 64;
            v = (i < 48) ? wkvI[o * 48 + i] : 0.f;
        } else if (t < 92160) {
            v = wpo[t - 55296];      // kept for symmetry (unused by GEMMs now)
        } else if (t < 239616) {
            v = wpin[t - 92160];     // unused (W'pin built in setup2)
        } else {
            v = wpout[t - 239616];
        }
        wb[t] = f2bf(v);
    } else if (t < 314112) {
        int r = t - 313344;              // modulation GEMVs (stored as val+1)
        if (r < 288) {
            int b = r / 144, o = r % 144;
            const float* v = kvv + b * 256;
            const float* w = wkR + o * 192;
            float s = 0.f;
            for (int j = 0; j < 192; j++) s += v[j] * w[j];
            sm[r] = s + 1.0f;
        } else if (r < 384) {
            int r2 = r - 288;
            int b = r2 / 48, o = r2 % 48;
            const float* v = kvv + b * 256 + 192;
            const float* w = wkI + o * 64;
            float s = 0.f;
            for (int j = 0; j < 64; j++) s += v[j] * w[j];
            sm[288 + r2] = s + 1.0f;
        } else {
            int r2 = r - 384;
            int b = r2 / 192, o = r2 % 192;
            const float* v = kvv + b * 256;
            const float* w = wffk + o * 256;
            float s = 0.f;
            for (int j = 0; j < 256; j++) s += v[j] * w[j];
            sm[384 + r2] = s + 1.0f;
        }
    } else if (t < 314624) {
        int r = t - 314112;
        tail[r] = kvv[r];                // k_v pass-through to output tail
    } else if (t < 326912) {
        sm[3840 + (t - 314624)] = 0.f;   // zero Smat [12][1024]
    }
}

// ---------------- K0b: build folded pin weights (LN2+mod folded into W) ------
__global__ void k_setup2(const float* __restrict__ wpin, const float* __restrict__ lnw,
                         const float* __restrict__ lnb, const float* __restrict__ kvf,
                         u16* __restrict__ wpinb, float* __restrict__ rsum,
                         float* __restrict__ biasp) {
    int t = blockIdx.x * 256 + threadIdx.x;   // 1536
    if (t >= 1536) return;
    int b = t / 768, m = t % 768;
    float rs = 0.f, bi = 0.f;
    u16* wrow = wpinb + (size_t)t * 192;
    for (int c = 0; c < 192; c++) {
        float w = wpin[m * 192 + c];
        float s = kvf[b * 192 + c];
        u16 h = f2bf(w * lnw[c] * s);
        wrow[c] = h;
        rs += bf2f(h);
        bi += w * lnb[c] * s;
    }
    rsum[t] = rs;
    biasp[t] = bi;
}

// ---------------- K1: LN1 + modulation -> xr,xi (bf16) + raw x (bf16) --------
__global__ __launch_bounds__(256) void k_ln1(
    const float* __restrict__ x,
    const float* __restrict__ lnw, const float* __restrict__ lnb,
    const float* __restrict__ sca, const float* __restrict__ scb,
    u16* __restrict__ outA, u16* __restrict__ outB, u16* __restrict__ xb16) {
    __shared__ float red[2][16][16][4];
    __shared__ float mu_s[16][4], rstd_s[16][4];
    int t = threadIdx.x;
    int px4 = t & 15, cg = t >> 4;
    int base = blockIdx.x * 64;
    int b = base >> 14;
    int p = (base & 16383) + px4 * 4;
    float vals[12][4];
    float s[4] = {0.f, 0.f, 0.f, 0.f}, s2[4] = {0.f, 0.f, 0.f, 0.f};
#pragma unroll
    for (int j = 0; j < 12; j++) {
        int c = cg * 12 + j;
        size_t off = ((size_t)(b * CDIM + c)) * HW + p;
        float4 f = *(const float4*)(x + off);
        float v[4] = {f.x, f.y, f.z, f.w};
        ushort4 o;
        o.x = f2bf(v[0]); o.y = f2bf(v[1]); o.z = f2bf(v[2]); o.w = f2bf(v[3]);
        *(ushort4*)(xb16 + off) = o;
#pragma unroll
        for (int q = 0; q < 4; q++) { vals[j][q] = v[q]; s[q] += v[q]; s2[q] += v[q] * v[q]; }
    }
#pragma unroll
    for (int q = 0; q < 4; q++) { red[0][cg][px4][q] = s[q]; red[1][cg][px4][q] = s2[q]; }
    __syncthreads();
    if (t < 16) {
        float S[4] = {0.f, 0.f, 0.f, 0.f}, S2[4] = {0.f, 0.f, 0.f, 0.f};
        for (int g2 = 0; g2 < 16; g2++)
#pragma unroll
            for (int q = 0; q < 4; q++) { S[q] += red[0][g2][t][q]; S2[q] += red[1][g2][t][q]; }
#pragma unroll
        for (int q = 0; q < 4; q++) {
            float mu = S[q] * (1.0f / CDIM);
            float var = S2[q] * (1.0f / CDIM) - mu * mu;
            mu_s[t][q] = mu;
            rstd_s[t][q] = rsqrtf(var + 1e-5f);
        }
    }
    __syncthreads();
    float mu[4], rs[4];
#pragma unroll
    for (int q = 0; q < 4; q++) { mu[q] = mu_s[px4][q]; rs[q] = rstd_s[px4][q]; }
#pragma unroll
    for (int j = 0; j < 12; j++) {
        int c = cg * 12 + j;
        float w = lnw[c], bb = lnb[c];
        float sc; u16* op; size_t off;
        if (c < C3) { sc = sca[b * C3 + c]; off = ((size_t)(b * C3 + c)) * HW + p; op = outA; }
        else { sc = scb[b * C4 + c - C3]; off = ((size_t)(b * C4 + c - C3)) * HW + p; op = outB; }
        ushort4 o;
        o.x = f2bf(((vals[j][0] - mu[0]) * rs[0] * w + bb) * sc);
        o.y = f2bf(((vals[j][1] - mu[1]) * rs[1] * w + bb) * sc);
        o.z = f2bf(((vals[j][2] - mu[2]) * rs[2] * w + bb) * sc);
        o.w = f2bf(((vals[j][3] - mu[3]) * rs[3] * w + bb) * sc);
        *(ushort4*)(op + off) = o;
    }
}

// ---------------- K2a: merged q/kv conv1x1 MFMA GEMM (LDS-staged) ------------
__global__ __launch_bounds__(256) void k_gemm_qkv(
    const u16* __restrict__ Xq, const u16* __restrict__ Xkv,
    const u16* __restrict__ Wq, const u16* __restrict__ Wkv,
    u16* __restrict__ Oq, u16* __restrict__ Okv) {
    __shared__ __align__(16) u16 Ws[64 * 32];
    __shared__ __align__(16) u16 Xs[32 * 130];
    const int tid = threadIdx.x;
    const int n0 = blockIdx.x * 128;
    const int y = blockIdx.y;
    const int b = blockIdx.z;
    const u16* X; const u16* Wb; u16* Op; int nch, cip, xrows, CO, m0;
    if (y < 3) { X = Xq; Wb = Wq; Op = Oq; nch = 5; cip = 160; xrows = 144; CO = 192; m0 = y * 64; }
    else { X = Xkv; Wb = Wkv; Op = Okv; nch = 2; cip = 64; xrows = 48; CO = 384; m0 = (y - 3) * 64; }
    const u16* Xb = X + (size_t)b * xrows * HW + n0;
    const int wave = tid >> 6, lane = tid & 63;
    const int quad = lane >> 4, l16 = lane & 15;
    const int smr = tid >> 2, sk4 = tid & 3;
    const int skr = tid >> 3, sc0 = (tid & 7) * 16;
    f32x4 acc[4][2] = {};
    for (int ch = 0; ch < nch; ch++) {
        const int k0 = ch * 32;
        if (ch) __syncthreads();
        {
            const int4 wv = *(const int4*)(Wb + (size_t)(m0 + smr) * cip + k0 + sk4 * 8);
            *(int4*)&Ws[(smr << 5) + (((sk4 ^ (smr & 3)) & 3) << 3)] = wv;
        }
        {
            const u16* xc = Xb + (size_t)(k0 + skr) * HW + sc0;
            int4 r0 = *(const int4*)xc;
            int4 r1 = *(const int4*)(xc + 8);
            u32* dst = (u32*)&Xs[skr * 130 + sc0];
#pragma unroll
            for (int i = 0; i < 4; i++) dst[i] = ((const u32*)&r0)[i];
#pragma unroll
            for (int i = 0; i < 4; i++) dst[4 + i] = ((const u32*)&r1)[i];
        }
        __syncthreads();
        bf16x8 af[4];
#pragma unroll
        for (int mi = 0; mi < 4; mi++) {
            int row = mi * 16 + l16;
            af[mi] = *(const bf16x8*)&Ws[(row << 5) + ((quad ^ (row & 3)) << 3)];
        }
#pragma unroll
        for (int ni = 0; ni < 2; ni++) {
            int n = wave * 32 + ni * 16 + l16;
            bf16x8 bfr;
#pragma unroll
            for (int j = 0; j < 8; j++) bfr[j] = (short)Xs[(quad * 8 + j) * 130 + n];
#pragma unroll
            for (int mi = 0; mi < 4; mi++)
                acc[mi][ni] = __builtin_amdgcn_mfma_f32_16x16x32_bf16(af[mi], bfr, acc[mi][ni], 0, 0, 0);
        }
    }
#pragma unroll
    for (int mi = 0; mi < 4; mi++)
#pragma unroll
        for (int ni = 0; ni < 2; ni++)
#pragma unroll
            for (int r = 0; r < 4; r++) {
                int m = m0 + mi * 16 + quad * 4 + r;
                int n = n0 + wave * 32 + ni * 16 + l16;
                Op[((size_t)b * CO + m) * HW + n] = f2bf(acc[mi][ni][r]);
            }
}

// ---------------- K3: merged depthwise 3x3 (q & kv), fused sumsq partials ----
__global__ __launch_bounds__(256) void k_dw2m(const u16* __restrict__ Xq,
                                              const u16* __restrict__ Xkv,
                                              const float* __restrict__ Wdq,
                                              const float* __restrict__ Wdkv,
                                              u16* __restrict__ outq, u16* __restrict__ outkv,
                                              float* __restrict__ sqq, float* __restrict__ sqk) {
    __shared__ float In[34 * 132];
    __shared__ float red[4];
    int bid = blockIdx.x;
    const u16* X; const float* Wd; u16* out; float* sqp; int C;
    if (bid < 1536) { X = Xq; Wd = Wdq; out = outq; sqp = sqq; C = 192; }
    else { bid -= 1536; X = Xkv; Wd = Wdkv; out = outkv; sqp = sqk; C = 384; }
    int bc = bid >> 2, rt = bid & 3;
    int b = bc / C, ch = bc % C;
    const u16* xb = X + (size_t)bc * HW;
    int t = threadIdx.x;
    int c0 = (t & 7) * 16;
    for (int r = t >> 3; r < 34; r += 32) {
        int y = rt * 32 - 1 + r;
        float* dst = &In[r * 132 + 1 + c0];
        if ((unsigned)y < 128u) {
            const u16* src = xb + y * 128 + c0;
            int4 r0 = *(const int4*)src;
            int4 r1 = *(const int4*)(src + 8);
            const u16* p0 = (const u16*)&r0;
            const u16* p1 = (const u16*)&r1;
#pragma unroll
            for (int i = 0; i < 8; i++) dst[i] = bf2f(p0[i]);
#pragma unroll
            for (int i = 0; i < 8; i++) dst[8 + i] = bf2f(p1[i]);
        } else {
#pragma unroll
            for (int i = 0; i < 16; i++) dst[i] = 0.f;
        }
    }
    if (t < 34) { In[t * 132] = 0.f; In[t * 132 + 129] = 0.f; }
    __syncthreads();
    const float* w = Wd + ch * 9;
    float w00 = w[0], w01 = w[1], w02 = w[2], w10 = w[3], w11 = w[4],
          w12 = w[5], w20 = w[6], w21 = w[7], w22 = w[8];
    int x = t & 127, rg = t >> 7;
    int base = rg * 16;
    float A2 = 0.f, A1 = 0.f, B1 = 0.f, ssq = 0.f;
    u16* ob = out + (size_t)bc * HW + (rt * 32 + base) * 128 + x;
#pragma unroll
    for (int r = 0; r < 18; r++) {
        const float* row = &In[(base + r) * 132 + x];
        float v0 = row[0], v1 = row[1], v2 = row[2];
        float h0 = w00 * v0 + w01 * v1 + w02 * v2;
        float h1 = w10 * v0 + w11 * v1 + w12 * v2;
        float h2 = w20 * v0 + w21 * v1 + w22 * v2;
        if (r >= 2) {
            float val = A2 + B1 + h2;
            ob[(size_t)(r - 2) * 128] = f2bf(val);
            ssq += val * val;
        }
        A2 = A1; A1 = h0; B1 = h1;
    }
    if (ch < 192) {   // block-uniform
        for (int o = 32; o > 0; o >>= 1) ssq += __shfl_down(ssq, o, 64);
        int wid = t >> 6, lane = t & 63;
        if (lane == 0) red[wid] = ssq;
        __syncthreads();
        if (t == 0) sqp[((b * 192 + ch) << 2) | rt] = red[0] + red[1] + red[2] + red[3];
    }
}

// ---------------- K4: S += Q*K^T via MFMA straight from global (atomics) -----
__global__ __launch_bounds__(256) void k_qk(const u16* __restrict__ qb_,
                                            const u16* __restrict__ kb_,
                                            float* __restrict__ S) {
    int bh = blockIdx.x >> 5, ds = blockIdx.x & 31;   // 384 blocks
    int b = bh / HEADS, h = bh % HEADS;
    int tid = threadIdx.x;
    int wave = tid >> 6, lane = tid & 63;
    int quad = lane >> 4, l16 = lane & 15;
    int tm = wave >> 1, tn = wave & 1;
    const u16* qrow = qb_ + ((size_t)(b * 192 + h * 32 + tm * 16 + l16)) * HW + ds * 512 + quad * 8;
    const u16* krow = kb_ + ((size_t)(b * 384 + h * 32 + tn * 16 + l16)) * HW + ds * 512 + quad * 8;
    f32x4 acc = {};
#pragma unroll
    for (int ch = 0; ch < 16; ch++) {
        bf16x8 a = *(const bf16x8*)(qrow + ch * 32);
        bf16x8 k8 = *(const bf16x8*)(krow + ch * 32);
        acc = __builtin_amdgcn_mfma_f32_16x16x32_bf16(a, k8, acc, 0, 0, 0);
    }
    float* Sb = S + bh * 1024;
#pragma unroll
    for (int r = 0; r < 4; r++)
        atomicAdd(&Sb[(tm * 16 + quad * 4 + r) * 32 + tn * 16 + l16], acc[r]);
}

// ---------------- K5: softmax + fold attn into po weights: Weff = Wpo @ bd(A) -
__global__ __launch_bounds__(256) void k_smA(const float* __restrict__ S,
                                             const float* __restrict__ sqqp,
                                             const float* __restrict__ sqkp,
                                             const float* __restrict__ temp,
                                             const float* __restrict__ wpo,
                                             u16* __restrict__ weff) {
    __shared__ float A[32][33];
    __shared__ float scq[32], sck[32];
    int bh = blockIdx.x;
    int b = bh / HEADS, h = bh % HEADS;
    int t = threadIdx.x;
    if (t < 32) {
        const float* qp = sqqp + (b * 192 + h * 32 + t) * 4;
        const float* kp = sqkp + (b * 192 + h * 32 + t) * 4;
        scq[t] = 1.0f / fmaxf(sqrtf(qp[0] + qp[1] + qp[2] + qp[3]), 1e-12f);
        sck[t] = 1.0f / fmaxf(sqrtf(kp[0] + kp[1] + kp[2] + kp[3]), 1e-12f);
    }
    __syncthreads();
    float tmp = temp[h];
    for (int idx = t; idx < 1024; idx += 256) {
        int r = idx >> 5, e = idx & 31;
        A[r][e] = S[bh * 1024 + r * 32 + e] * scq[r] * sck[e] * tmp;
    }
    __syncthreads();
    if (t < 32) {
        float m = -1e30f;
        for (int e = 0; e < 32; e++) m = fmaxf(m, A[t][e]);
        float s = 0.f;
        for (int e = 0; e < 32; e++) { float ev = expf(A[t][e] - m); A[t][e] = ev; s += ev; }
        float inv = 1.0f / s;
        for (int e = 0; e < 32; e++) A[t][e] *= inv;
    }
    __syncthreads();
    for (int idx = t; idx < 6144; idx += 256) {
        int m = idx >> 5, e = idx & 31;
        float s = 0.f;
        const float* wr = wpo + m * 192 + h * 32;
#pragma unroll 8
        for (int c = 0; c < 32; c++) s += wr[c] * A[c][e];
        weff[((size_t)b * 192 + m) * 192 + h * 32 + e] = f2bf(s);
    }
}

// ---------------- K6: po GEMM: x1 = Weff@V + x; out T-layout + LN2 stats -----
__global__ __launch_bounds__(256) void k_gemm_po(
    const u16* __restrict__ kvb, const u16* __restrict__ weff,
    const u16* __restrict__ residb, u16* __restrict__ outT,
    float* __restrict__ sumP, float* __restrict__ sum2P) {
    __shared__ __align__(16) u16 Ws[64 * 32];
    __shared__ __align__(16) u16 Xs[32 * 130];
    __shared__ __align__(16) u16 Lx[128 * 72];
    const int tid = threadIdx.x;
    const int n0 = blockIdx.x * 128;
    const int m0 = blockIdx.y * 64;
    const int b = blockIdx.z;
    const u16* Xb = kvb + ((size_t)b * 384 + 192) * HW + n0;   // V rows
    const u16* Wb = weff + (size_t)b * 192 * 192;
    const int wave = tid >> 6, lane = tid & 63;
    const int quad = lane >> 4, l16 = lane & 15;
    const int smr = tid >> 2, sk4 = tid & 3;
    const int skr = tid >> 3, sc0 = (tid & 7) * 16;
    f32x4 acc[4][2] = {};
    for (int ch = 0; ch < 6; ch++) {
        const int k0 = ch * 32;
        if (ch) __syncthreads();
        {
            const int4 wv = *(const int4*)(Wb + (size_t)(m0 + smr) * 192 + k0 + sk4 * 8);
            *(int4*)&Ws[(smr << 5) + (((sk4 ^ (smr & 3)) & 3) << 3)] = wv;
        }
        {
            const u16* xc = Xb + (size_t)(k0 + skr) * HW + sc0;
            int4 r0 = *(const int4*)xc;
            int4 r1 = *(const int4*)(xc + 8);
            u32* dst = (u32*)&Xs[skr * 130 + sc0];
#pragma unroll
            for (int i = 0; i < 4; i++) dst[i] = ((const u32*)&r0)[i];
#pragma unroll
            for (int i = 0; i < 4; i++) dst[4 + i] = ((const u32*)&r1)[i];
        }
        __syncthreads();
        bf16x8 af[4];
#pragma unroll
        for (int mi = 0; mi < 4; mi++) {
            int row = mi * 16 + l16;
            af[mi] = *(const bf16x8*)&Ws[(row << 5) + ((quad ^ (row & 3)) << 3)];
        }
#pragma unroll
        for (int ni = 0; ni < 2; ni++) {
            int n = wave * 32 + ni * 16 + l16;
            bf16x8 bfr;
#pragma unroll
            for (int j = 0; j < 8; j++) bfr[j] = (short)Xs[(quad * 8 + j) * 130 + n];
#pragma unroll
            for (int mi = 0; mi < 4; mi++)
                acc[mi][ni] = __builtin_amdgcn_mfma_f32_16x16x32_bf16(af[mi], bfr, acc[mi][ni], 0, 0, 0);
        }
    }
    // epilogue: add bf16 x residual, stats partials, transpose to T-layout
    float s1[2] = {0.f, 0.f}, s2[2] = {0.f, 0.f};
#pragma unroll
    for (int ni = 0; ni < 2; ni++) {
        int nl = wave * 32 + ni * 16 + l16;
#pragma unroll
        for (int mi = 0; mi < 4; mi++)
#pragma unroll
            for (int r = 0; r < 4; r++) {
                int mloc = mi * 16 + quad * 4 + r;
                float v = acc[mi][ni][r] +
                          bf2f(residb[((size_t)(b * 192 + m0 + mloc)) * HW + n0 + nl]);
                s1[ni] += v; s2[ni] += v * v;
                Lx[nl * 72 + mloc] = f2bf(v);
            }
        float a = s1[ni], c = s2[ni];
        a += __shfl_xor(a, 16, 64); a += __shfl_xor(a, 32, 64);
        c += __shfl_xor(c, 16, 64); c += __shfl_xor(c, 32, 64);
        if (quad == 0) {
            sumP[((size_t)(b * 3 + blockIdx.y)) * HW + n0 + nl] = a;
            sum2P[((size_t)(b * 3 + blockIdx.y)) * HW + n0 + nl] = c;
        }
    }
    __syncthreads();
    {
        int n = tid & 127, chunk = tid >> 7;
        const int4* src = (const int4*)&Lx[n * 72 + chunk * 32];
        int4 a0 = src[0], a1 = src[1], a2 = src[2], a3 = src[3];
        int4* dst = (int4*)(outT + ((size_t)(b * 6 + (m0 >> 5) + chunk) * HW + n0 + n) * 32);
        dst[0] = a0; dst[1] = a1; dst[2] = a2; dst[3] = a3;
    }
}

// ---------------- K7: pin GEMM, LDS-free from T-layout x1, fused LN2 epilogue -
__global__ __launch_bounds__(256) void k_pin(
    const u16* __restrict__ xT, const u16* __restrict__ wpb,
    const float* __restrict__ rsum, const float* __restrict__ biasp,
    const float* __restrict__ sumP, const float* __restrict__ sum2P,
    u16* __restrict__ out) {
    const int tid = threadIdx.x;
    const int n0 = blockIdx.x * 128;
    const int m0 = blockIdx.y * 64;
    const int b = blockIdx.z;
    const int wave = tid >> 6, lane = tid & 63;
    const int quad = lane >> 4, l16 = lane & 15;
    const u16* wbase = wpb + ((size_t)(b * 768 + m0)) * 192;
    f32x4 acc[4][2] = {};
#pragma unroll
    for (int ch = 0; ch < 6; ch++) {
        bf16x8 af[4];
#pragma unroll
        for (int mi = 0; mi < 4; mi++)
            af[mi] = *(const bf16x8*)(wbase + (size_t)(mi * 16 + l16) * 192 + ch * 32 + quad * 8);
#pragma unroll
        for (int ni = 0; ni < 2; ni++) {
            bf16x8 bfr = *(const bf16x8*)(xT +
                ((size_t)(b * 6 + ch) * HW + n0 + wave * 32 + ni * 16 + l16) * 32 + quad * 8);
#pragma unroll
            for (int mi = 0; mi < 4; mi++)
                acc[mi][ni] = __builtin_amdgcn_mfma_f32_16x16x32_bf16(af[mi], bfr, acc[mi][ni], 0, 0, 0);
        }
    }
    float rsv[4][4], biv[4][4];
#pragma unroll
    for (int mi = 0; mi < 4; mi++)
#pragma unroll
        for (int r = 0; r < 4; r++) {
            int m = m0 + mi * 16 + quad * 4 + r;
            rsv[mi][r] = rsum[b * 768 + m];
            biv[mi][r] = biasp[b * 768 + m];
        }
#pragma unroll
    for (int ni = 0; ni < 2; ni++) {
        int n = n0 + wave * 32 + ni * 16 + l16;
        size_t sb = (size_t)b * 3 * HW + n;
        float P = sumP[sb] + sumP[sb + HW] + sumP[sb + 2 * HW];
        float Q = sum2P[sb] + sum2P[sb + HW] + sum2P[sb + 2 * HW];
        float mu = P * (1.0f / 192.0f);
        float var = Q * (1.0f / 192.0f) - mu * mu;
        float rstd = rsqrtf(var + 1e-5f);
#pragma unroll
        for (int mi = 0; mi < 4; mi++)
#pragma unroll
            for (int r = 0; r < 4; r++) {
                int m = m0 + mi * 16 + quad * 4 + r;
                float v = rstd * (acc[mi][ni][r] - mu * rsv[mi][r]) + biv[mi][r];
                out[((size_t)(b * 768 + m)) * HW + n] = f2bf(v);
            }
    }
}

// ---------------- K8: depthwise 3x3 pair + exact GELU gate, LDS-tiled --------
__global__ __launch_bounds__(256) void k_dw_gelu2(const u16* __restrict__ G0,
                                                  const float* __restrict__ Wd,
                                                  u16* __restrict__ out) {
    __shared__ float In[2 * 34 * 132];
    int bc = blockIdx.x >> 2, rt = blockIdx.x & 3;
    int b = bc / 384, j = bc % 384;
    int t = threadIdx.x;
    int c0 = (t & 7) * 16;
    for (int pl = 0; pl < 2; pl++) {
        const u16* xb = G0 + ((size_t)b * 768 + pl * 384 + j) * HW;
        float* pla = &In[pl * 34 * 132];
        for (int r = t >> 3; r < 34; r += 32) {
            int y = rt * 32 - 1 + r;
            float* dst = &pla[r * 132 + 1 + c0];
            if ((unsigned)y < 128u) {
                const u16* src = xb + y * 128 + c0;
                int4 r0 = *(const int4*)src;
                int4 r1 = *(const int4*)(src + 8);
                const u16* p0 = (const u16*)&r0;
                const u16* p1 = (const u16*)&r1;
#pragma unroll
                for (int i = 0; i < 8; i++) dst[i] = bf2f(p0[i]);
#pragma unroll
                for (int i = 0; i < 8; i++) dst[8 + i] = bf2f(p1[i]);
            } else {
#pragma unroll
                for (int i = 0; i < 16; i++) dst[i] = 0.f;
            }
        }
        if (t < 34) { pla[t * 132] = 0.f; pla[t * 132 + 129] = 0.f; }
    }
    __syncthreads();
    const float* w1 = Wd + j * 9;
    const float* w2 = Wd + (384 + j) * 9;
    float a00 = w1[0], a01 = w1[1], a02 = w1[2], a10 = w1[3], a11 = w1[4],
          a12 = w1[5], a20 = w1[6], a21 = w1[7], a22 = w1[8];
    float b00 = w2[0], b01 = w2[1], b02 = w2[2], b10 = w2[3], b11 = w2[4],
          b12 = w2[5], b20 = w2[6], b21 = w2[7], b22 = w2[8];
    int x = t & 127, rg = t >> 7;
    int base = rg * 16;
    float A2a = 0.f, A1a = 0.f, B1a = 0.f;
    float A2b = 0.f, A1b = 0.f, B1b = 0.f;
    u16* ob = out + ((size_t)b * 384 + j) * HW + (rt * 32 + base) * 128 + x;
#pragma unroll
    for (int r = 0; r < 18; r++) {
        const float* r1p = &In[(base + r) * 132 + x];
        const float* r2p = r1p + 34 * 132;
        float u0 = r1p[0], u1 = r1p[1], u2 = r1p[2];
        float v0 = r2p[0], v1 = r2p[1], v2 = r2p[2];
        float h0a = a00 * u0 + a01 * u1 + a02 * u2;
        float h1a = a10 * u0 + a11 * u1 + a12 * u2;
        float h2a = a20 * u0 + a21 * u1 + a22 * u2;
        float h0b = b00 * v0 + b01 * v1 + b02 * v2;
        float h1b = b10 * v0 + b11 * v1 + b12 * v2;
        float h2b = b20 * v0 + b21 * v1 + b22 * v2;
        if (r >= 2) {
            float s1 = A2a + B1a + h2a;
            float s2 = A2b + B1b + h2b;
            float g = 0.5f * s1 * (1.0f + erff(s1 * 0.70710678118654752f));
            ob[(size_t)(r - 2) * 128] = f2bf(g * s2);
        }
        A2a = A1a; A1a = h0a; B1a = h1a;
        A2b = A1b; A1b = h0b; B1b = h1b;
    }
}

// ---------------- K9: pout GEMM (LDS-staged), resid from T-layout x1, fp32 out
__global__ __launch_bounds__(256) void k_gemm_pout(
    const u16* __restrict__ X, const u16* __restrict__ Wb,
    const u16* __restrict__ residT, float* __restrict__ out) {
    __shared__ __align__(16) u16 Ws[64 * 32];
    __shared__ __align__(16) u16 Xs[32 * 130];
    const int tid = threadIdx.x;
    const int n0 = blockIdx.x * 128;
    const int m0 = blockIdx.y * 64;
    const int b = blockIdx.z;
    const u16* Xb = X + (size_t)b * 384 * HW + n0;
    const int wave = tid >> 6, lane = tid & 63;
    const int quad = lane >> 4, l16 = lane & 15;
    const int smr = tid >> 2, sk4 = tid & 3;
    const int skr = tid >> 3, sc0 = (tid & 7) * 16;
    f32x4 acc[4][2] = {};
    for (int ch = 0; ch < 12; ch++) {
        const int k0 = ch * 32;
        if (ch) __syncthreads();
        {
            const int4 wv = *(const int4*)(Wb + (size_t)(m0 + smr) * 384 + k0 + sk4 * 8);
            *(int4*)&Ws[(smr << 5) + (((sk4 ^ (smr & 3)) & 3) << 3)] = wv;
        }
        {
            const u16* xc = Xb + (size_t)(k0 + skr) * HW + sc0;
            int4 r0 = *(const int4*)xc;
            int4 r1 = *(const int4*)(xc + 8);
            u32* dst = (u32*)&Xs[skr * 130 + sc0];
#pragma unroll
            for (int i = 0; i < 4; i++) dst[i] = ((const u32*)&r0)[i];
#pragma unroll
            for (int i = 0; i < 4; i++) dst[4 + i] = ((const u32*)&r1)[i];
        }
        __syncthreads();
        bf16x8 af[4];
#pragma unroll
        for (int mi = 0; mi < 4; mi++) {
            int row = mi * 16 + l16;
            af[mi] = *(const bf16x8*)&Ws[(row << 5) + ((quad ^ (row & 3)) << 3)];
        }
#pragma unroll
        for (int ni = 0; ni < 2; ni++) {
            int n = wave * 32 + ni * 16 + l16;
            bf16x8 bfr;
#pragma unroll
            for (int j = 0; j < 8; j++) bfr[j] = (short)Xs[(quad * 8 + j) * 130 + n];
#pragma unroll
            for (int mi = 0; mi < 4; mi++)
                acc[mi][ni] = __builtin_amdgcn_mfma_f32_16x16x32_bf16(af[mi], bfr, acc[mi][ni], 0, 0, 0);
        }
    }
#pragma unroll
    for (int mi = 0; mi < 4; mi++)
#pragma unroll
        for (int ni = 0; ni < 2; ni++)
#pragma unroll
            for (int r = 0; r < 4; r++) {
                int m = m0 + mi * 16 + quad * 4 + r;
                int n = n0 + wave * 32 + ni * 16 + l16;
                float v = acc[mi][ni][r] +
                          bf2f(residT[((size_t)(b * 6 + (m >> 5)) * HW + n) * 32 + (m & 31)]);
                out[((size_t)(b * 192 + m)) * HW + n] = v;
            }
}

extern "C" void kernel_launch(void* const* d_in, const int* in_sizes, int n_in,
                              void* d_out, int out_size, void* d_ws, size_t ws_size,
                              hipStream_t stream) {
    const float* x     = (const float*)d_in[0];
    const float* k_v   = (const float*)d_in[1];
    const float* ln1w  = (const float*)d_in[2];
    const float* ln1b  = (const float*)d_in[3];
    const float* temp  = (const float*)d_in[4];
    const float* w_kR  = (const float*)d_in[5];
    const float* w_kI  = (const float*)d_in[6];
    const float* w_qR  = (const float*)d_in[7];
    const float* w_qdw = (const float*)d_in[8];
    const float* w_kvI = (const float*)d_in[9];
    const float* w_kvdw= (const float*)d_in[10];
    const float* w_po  = (const float*)d_in[11];
    const float* ln2w  = (const float*)d_in[12];
    const float* ln2b  = (const float*)d_in[13];
    const float* w_ffk = (const float*)d_in[14];
    const float* w_pin = (const float*)d_in[15];
    const float* w_dw  = (const float*)d_in[16];
    const float* w_pout= (const float*)d_in[17];
    float* out = (float*)d_out;

    const size_t MiB = 1048576ULL;
    u16*   q0b     = wsh(d_ws, 0);           // [2][192] bf16
    u16*   kv0b    = wsh(d_ws, 16 * MiB);    // [2][384] bf16
    u16*   qbuf_b  = wsh(d_ws, 40 * MiB);    // [2][192] bf16
    u16*   kvbuf_b = wsh(d_ws, 56 * MiB);    // [2][384] bf16
    u16*   xrb     = wsh(d_ws, 80 * MiB);    // [2][144] bf16 + overread slack
    u16*   xib     = wsh(d_ws, 90 * MiB);    // [2][48] bf16 + slack
    u16*   xb16    = wsh(d_ws, 94 * MiB);    // [2][192] raw x bf16
    u16*   x1T     = wsh(d_ws, 106 * MiB);   // [2][6][HW][32] tiled x1 bf16
    u16*   g0b     = wsh(d_ws, 118 * MiB);   // [2][768] bf16
    u16*   ybufb   = wsh(d_ws, 166 * MiB);   // [2][384] bf16
    u16*   wb      = wsh(d_ws, 190 * MiB);   // bf16 weights
    u16*   weffb   = wsh(d_ws, 191 * MiB);   // [2][192][192] bf16
    u16*   wpinb   = wsh(d_ws, 192 * MiB);   // [2][768][192] bf16
    float* sm      = wsf(d_ws, 194 * MiB);   // smalls
    float* sumP    = wsf(d_ws, 196 * MiB);   // [2][3][HW]
    float* sum2P   = wsf(d_ws, 197 * MiB);   // [2][3][HW]
    u16* wq   = wb;            // [192][160]
    u16* wkv  = wb + 30720;    // [384][64]
    u16* wpout= wb + 239616;   // [192][384]
    float* kvr  = sm;               // 288
    float* kvi  = sm + 288;         // 96
    float* kvf  = sm + 384;         // 384
    float* sqqp = sm + 768;         // 1536
    float* sqkp = sm + 2304;        // 1536
    float* Smat = sm + 3840;        // 12288
    float* rsum = sm + 16128;       // 1536
    float* biasp= sm + 17664;       // 1536

    k_setup<<<1277, 256, 0, stream>>>(k_v, w_kR, w_kI, w_ffk, w_qR, w_kvI, w_po,
                                      w_pin, w_pout, wb, sm,
                                      out + (size_t)NB * CDIM * HW);
    k_setup2<<<6, 256, 0, stream>>>(w_pin, ln2w, ln2b, kvf, wpinb, rsum, biasp);
    k_ln1<<<NPX / 64, 256, 0, stream>>>(x, ln1w, ln1b, kvr, kvi, xrb, xib, xb16);
    k_gemm_qkv<<<dim3(128, 9, 2), 256, 0, stream>>>(xrb, xib, wq, wkv, q0b, kv0b);
    k_dw2m<<<4608, 256, 0, stream>>>(q0b, kv0b, w_qdw, w_kvdw, qbuf_b, kvbuf_b, sqqp, sqkp);
    k_qk<<<12 * 32, 256, 0, stream>>>(qbuf_b, kvbuf_b, Smat);
    k_smA<<<12, 256, 0, stream>>>(Smat, sqqp, sqkp, temp, w_po, weffb);
    k_gemm_po<<<dim3(128, 3, 2), 256, 0, stream>>>(kvbuf_b, weffb, xb16, x1T, sumP, sum2P);
    k_pin<<<dim3(128, 12, 2), 256, 0, stream>>>(x1T, wpinb, rsum, biasp, sumP, sum2P, g0b);
    k_dw_gelu2<<<NB * 384 * 4, 256, 0, stream>>>(g0b, w_dw, ybufb);
    k_gemm_pout<<<dim3(128, 3, 2), 256, 0, stream>>>(ybufb, wpout, x1T, out);
}

// Round 6
// 280.553 us; speedup vs baseline: 1.0937x; 1.0937x over previous
//
#include <hip/hip_runtime.h>
#include <math.h>

#define HW 16384
#define IMG 128
#define CDIM 192
#define C3 144
#define C4 48
#define NB 2
#define NPX 32768   // NB*HW
#define HEADS 6

typedef unsigned short u16;
typedef unsigned int u32;
typedef __attribute__((ext_vector_type(8))) short bf16x8;
typedef __attribute__((ext_vector_type(4))) float f32x4;

__device__ __forceinline__ float bf2f(u16 u) {
    return __uint_as_float(((unsigned int)u) << 16);
}
__device__ __forceinline__ u16 f2bf(float f) {
    unsigned int x = __float_as_uint(f);
    unsigned int r = x + 0x7fffu + ((x >> 16) & 1u);  // RNE
    return (u16)(r >> 16);
}

static inline float* wsf(void* ws, size_t off) { return (float*)((char*)ws + off); }
static inline u16* wsh(void* ws, size_t off) { return (u16*)((char*)ws + off); }

// ---------------- K0: setup = weight bf16 conv + tiny GEMVs + tail + S zero --
// wb layout: wq[192][160] | wkv[384][64] | ... | wpout @239616 [192][384]
__global__ void k_setup(const float* __restrict__ kvv, const float* __restrict__ wkR,
                        const float* __restrict__ wkI, const float* __restrict__ wffk,
                        const float* __restrict__ wqR, const float* __restrict__ wkvI,
                        const float* __restrict__ wpo, const float* __restrict__ wpin,
                        const float* __restrict__ wpout,
                        u16* __restrict__ wb, float* __restrict__ sm,
                        float* __restrict__ tail) {
    int t = blockIdx.x * 256 + threadIdx.x;
    if (t < 313344) {
        float v;
        if (t < 30720) {
            int o = t / 160, i = t % 160;
            v = (i < 144) ? wqR[o * 144 + i] : 0.f;
        } else if (t < 55296) {
            int r = t - 30720; int o = r / 64, i = r % 64;
            v = (i < 48) ? wkvI[o * 48 + i] : 0.f;
        } else if (t < 92160) {
            v = wpo[t - 55296];      // unused by GEMMs (attn folded) — harmless
        } else if (t < 239616) {
            v = wpin[t - 92160];     // unused (W'pin built in setup2) — harmless
        } else {
            v = wpout[t - 239616];
        }
        wb[t] = f2bf(v);
    } else if (t < 314112) {
        int r = t - 313344;              // modulation GEMVs (stored as val+1)
        if (r < 288) {
            int b = r / 144, o = r % 144;
            const float* v = kvv + b * 256;
            const float* w = wkR + o * 192;
            float s = 0.f;
            for (int j = 0; j < 192; j++) s += v[j] * w[j];
            sm[r] = s + 1.0f;
        } else if (r < 384) {
            int r2 = r - 288;
            int b = r2 / 48, o = r2 % 48;
            const float* v = kvv + b * 256 + 192;
            const float* w = wkI + o * 64;
            float s = 0.f;
            for (int j = 0; j < 64; j++) s += v[j] * w[j];
            sm[288 + r2] = s + 1.0f;
        } else {
            int r2 = r - 384;
            int b = r2 / 192, o = r2 % 192;
            const float* v = kvv + b * 256;
            const float* w = wffk + o * 256;
            float s = 0.f;
            for (int j = 0; j < 256; j++) s += v[j] * w[j];
            sm[384 + r2] = s + 1.0f;
        }
    } else if (t < 314624) {
        int r = t - 314112;
        tail[r] = kvv[r];                // k_v pass-through to output tail
    } else if (t < 326912) {
        sm[3840 + (t - 314624)] = 0.f;   // zero Smat [12][1024]
    }
}

// ---------------- K0b: build folded pin weights (LN2+mod folded into W) ------
__global__ void k_setup2(const float* __restrict__ wpin, const float* __restrict__ lnw,
                         const float* __restrict__ lnb, const float* __restrict__ kvf,
                         u16* __restrict__ wpinb, float* __restrict__ rsum,
                         float* __restrict__ biasp) {
    int t = blockIdx.x * 256 + threadIdx.x;   // 1536
    if (t >= 1536) return;
    int b = t / 768, m = t % 768;
    float rs = 0.f, bi = 0.f;
    u16* wrow = wpinb + (size_t)t * 192;
    for (int c = 0; c < 192; c++) {
        float w = wpin[m * 192 + c];
        float s = kvf[b * 192 + c];
        u16 h = f2bf(w * lnw[c] * s);
        wrow[c] = h;
        rs += bf2f(h);
        bi += w * lnb[c] * s;
    }
    rsum[t] = rs;
    biasp[t] = bi;
}

// ---------------- K1: LN1 + modulation -> xr,xi (bf16) + raw x (bf16) --------
__global__ __launch_bounds__(256) void k_ln1(
    const float* __restrict__ x,
    const float* __restrict__ lnw, const float* __restrict__ lnb,
    const float* __restrict__ sca, const float* __restrict__ scb,
    u16* __restrict__ outA, u16* __restrict__ outB, u16* __restrict__ xb16) {
    __shared__ float red[2][16][16][4];
    __shared__ float mu_s[16][4], rstd_s[16][4];
    int t = threadIdx.x;
    int px4 = t & 15, cg = t >> 4;
    int base = blockIdx.x * 64;
    int b = base >> 14;
    int p = (base & 16383) + px4 * 4;
    float vals[12][4];
    float s[4] = {0.f, 0.f, 0.f, 0.f}, s2[4] = {0.f, 0.f, 0.f, 0.f};
#pragma unroll
    for (int j = 0; j < 12; j++) {
        int c = cg * 12 + j;
        size_t off = ((size_t)(b * CDIM + c)) * HW + p;
        float4 f = *(const float4*)(x + off);
        float v[4] = {f.x, f.y, f.z, f.w};
        ushort4 o;
        o.x = f2bf(v[0]); o.y = f2bf(v[1]); o.z = f2bf(v[2]); o.w = f2bf(v[3]);
        *(ushort4*)(xb16 + off) = o;
#pragma unroll
        for (int q = 0; q < 4; q++) { vals[j][q] = v[q]; s[q] += v[q]; s2[q] += v[q] * v[q]; }
    }
#pragma unroll
    for (int q = 0; q < 4; q++) { red[0][cg][px4][q] = s[q]; red[1][cg][px4][q] = s2[q]; }
    __syncthreads();
    if (t < 16) {
        float S[4] = {0.f, 0.f, 0.f, 0.f}, S2[4] = {0.f, 0.f, 0.f, 0.f};
        for (int g2 = 0; g2 < 16; g2++)
#pragma unroll
            for (int q = 0; q < 4; q++) { S[q] += red[0][g2][t][q]; S2[q] += red[1][g2][t][q]; }
#pragma unroll
        for (int q = 0; q < 4; q++) {
            float mu = S[q] * (1.0f / CDIM);
            float var = S2[q] * (1.0f / CDIM) - mu * mu;
            mu_s[t][q] = mu;
            rstd_s[t][q] = rsqrtf(var + 1e-5f);
        }
    }
    __syncthreads();
    float mu[4], rs[4];
#pragma unroll
    for (int q = 0; q < 4; q++) { mu[q] = mu_s[px4][q]; rs[q] = rstd_s[px4][q]; }
#pragma unroll
    for (int j = 0; j < 12; j++) {
        int c = cg * 12 + j;
        float w = lnw[c], bb = lnb[c];
        float sc; u16* op; size_t off;
        if (c < C3) { sc = sca[b * C3 + c]; off = ((size_t)(b * C3 + c)) * HW + p; op = outA; }
        else { sc = scb[b * C4 + c - C3]; off = ((size_t)(b * C4 + c - C3)) * HW + p; op = outB; }
        ushort4 o;
        o.x = f2bf(((vals[j][0] - mu[0]) * rs[0] * w + bb) * sc);
        o.y = f2bf(((vals[j][1] - mu[1]) * rs[1] * w + bb) * sc);
        o.z = f2bf(((vals[j][2] - mu[2]) * rs[2] * w + bb) * sc);
        o.w = f2bf(((vals[j][3] - mu[3]) * rs[3] * w + bb) * sc);
        *(ushort4*)(op + off) = o;
    }
}

// ---------------- K2: merged q/kv conv1x1 MFMA GEMM (LDS-staged) -------------
__global__ __launch_bounds__(256) void k_gemm_qkv(
    const u16* __restrict__ Xq, const u16* __restrict__ Xkv,
    const u16* __restrict__ Wq, const u16* __restrict__ Wkv,
    u16* __restrict__ Oq, u16* __restrict__ Okv) {
    __shared__ __align__(16) u16 Ws[64 * 32];
    __shared__ __align__(16) u16 Xs[32 * 130];
    const int tid = threadIdx.x;
    const int n0 = blockIdx.x * 128;
    const int y = blockIdx.y;
    const int b = blockIdx.z;
    const u16* X; const u16* Wb; u16* Op; int nch, cip, xrows, CO, m0;
    if (y < 3) { X = Xq; Wb = Wq; Op = Oq; nch = 5; cip = 160; xrows = 144; CO = 192; m0 = y * 64; }
    else { X = Xkv; Wb = Wkv; Op = Okv; nch = 2; cip = 64; xrows = 48; CO = 384; m0 = (y - 3) * 64; }
    const u16* Xb = X + (size_t)b * xrows * HW + n0;
    const int wave = tid >> 6, lane = tid & 63;
    const int quad = lane >> 4, l16 = lane & 15;
    const int smr = tid >> 2, sk4 = tid & 3;
    const int skr = tid >> 3, sc0 = (tid & 7) * 16;
    f32x4 acc[4][2] = {};
    for (int ch = 0; ch < nch; ch++) {
        const int k0 = ch * 32;
        if (ch) __syncthreads();
        {
            const int4 wv = *(const int4*)(Wb + (size_t)(m0 + smr) * cip + k0 + sk4 * 8);
            *(int4*)&Ws[(smr << 5) + (((sk4 ^ (smr & 3)) & 3) << 3)] = wv;
        }
        {
            const u16* xc = Xb + (size_t)(k0 + skr) * HW + sc0;
            int4 r0 = *(const int4*)xc;
            int4 r1 = *(const int4*)(xc + 8);
            u32* dst = (u32*)&Xs[skr * 130 + sc0];
#pragma unroll
            for (int i = 0; i < 4; i++) dst[i] = ((const u32*)&r0)[i];
#pragma unroll
            for (int i = 0; i < 4; i++) dst[4 + i] = ((const u32*)&r1)[i];
        }
        __syncthreads();
        bf16x8 af[4];
#pragma unroll
        for (int mi = 0; mi < 4; mi++) {
            int row = mi * 16 + l16;
            af[mi] = *(const bf16x8*)&Ws[(row << 5) + ((quad ^ (row & 3)) << 3)];
        }
#pragma unroll
        for (int ni = 0; ni < 2; ni++) {
            int n = wave * 32 + ni * 16 + l16;
            bf16x8 bfr;
#pragma unroll
            for (int j = 0; j < 8; j++) bfr[j] = (short)Xs[(quad * 8 + j) * 130 + n];
#pragma unroll
            for (int mi = 0; mi < 4; mi++)
                acc[mi][ni] = __builtin_amdgcn_mfma_f32_16x16x32_bf16(af[mi], bfr, acc[mi][ni], 0, 0, 0);
        }
    }
#pragma unroll
    for (int mi = 0; mi < 4; mi++)
#pragma unroll
        for (int ni = 0; ni < 2; ni++)
#pragma unroll
            for (int r = 0; r < 4; r++) {
                int m = m0 + mi * 16 + quad * 4 + r;
                int n = n0 + wave * 32 + ni * 16 + l16;
                Op[((size_t)b * CO + m) * HW + n] = f2bf(acc[mi][ni][r]);
            }
}

// ---------------- K3: merged depthwise 3x3 (q & kv), fused sumsq partials ----
__global__ __launch_bounds__(256) void k_dw2m(const u16* __restrict__ Xq,
                                              const u16* __restrict__ Xkv,
                                              const float* __restrict__ Wdq,
                                              const float* __restrict__ Wdkv,
                                              u16* __restrict__ outq, u16* __restrict__ outkv,
                                              float* __restrict__ sqq, float* __restrict__ sqk) {
    __shared__ float In[34 * 132];
    __shared__ float red[4];
    int bid = blockIdx.x;
    const u16* X; const float* Wd; u16* out; float* sqp; int C;
    if (bid < 1536) { X = Xq; Wd = Wdq; out = outq; sqp = sqq; C = 192; }
    else { bid -= 1536; X = Xkv; Wd = Wdkv; out = outkv; sqp = sqk; C = 384; }
    int bc = bid >> 2, rt = bid & 3;
    int b = bc / C, ch = bc % C;
    const u16* xb = X + (size_t)bc * HW;
    int t = threadIdx.x;
    int c0 = (t & 7) * 16;
    for (int r = t >> 3; r < 34; r += 32) {
        int y = rt * 32 - 1 + r;
        float* dst = &In[r * 132 + 1 + c0];
        if ((unsigned)y < 128u) {
            const u16* src = xb + y * 128 + c0;
            int4 r0 = *(const int4*)src;
            int4 r1 = *(const int4*)(src + 8);
            const u16* p0 = (const u16*)&r0;
            const u16* p1 = (const u16*)&r1;
#pragma unroll
            for (int i = 0; i < 8; i++) dst[i] = bf2f(p0[i]);
#pragma unroll
            for (int i = 0; i < 8; i++) dst[8 + i] = bf2f(p1[i]);
        } else {
#pragma unroll
            for (int i = 0; i < 16; i++) dst[i] = 0.f;
        }
    }
    if (t < 34) { In[t * 132] = 0.f; In[t * 132 + 129] = 0.f; }
    __syncthreads();
    const float* w = Wd + ch * 9;
    float w00 = w[0], w01 = w[1], w02 = w[2], w10 = w[3], w11 = w[4],
          w12 = w[5], w20 = w[6], w21 = w[7], w22 = w[8];
    int x = t & 127, rg = t >> 7;
    int base = rg * 16;
    float A2 = 0.f, A1 = 0.f, B1 = 0.f, ssq = 0.f;
    u16* ob = out + (size_t)bc * HW + (rt * 32 + base) * 128 + x;
#pragma unroll
    for (int r = 0; r < 18; r++) {
        const float* row = &In[(base + r) * 132 + x];
        float v0 = row[0], v1 = row[1], v2 = row[2];
        float h0 = w00 * v0 + w01 * v1 + w02 * v2;
        float h1 = w10 * v0 + w11 * v1 + w12 * v2;
        float h2 = w20 * v0 + w21 * v1 + w22 * v2;
        if (r >= 2) {
            float val = A2 + B1 + h2;
            ob[(size_t)(r - 2) * 128] = f2bf(val);
            ssq += val * val;
        }
        A2 = A1; A1 = h0; B1 = h1;
    }
    if (ch < 192) {   // block-uniform
        for (int o = 32; o > 0; o >>= 1) ssq += __shfl_down(ssq, o, 64);
        int wid = t >> 6, lane = t & 63;
        if (lane == 0) red[wid] = ssq;
        __syncthreads();
        if (t == 0) sqp[((b * 192 + ch) << 2) | rt] = red[0] + red[1] + red[2] + red[3];
    }
}

// ---------------- K4: S += Q*K^T via MFMA straight from global (atomics) -----
__global__ __launch_bounds__(256) void k_qk(const u16* __restrict__ qb_,
                                            const u16* __restrict__ kb_,
                                            float* __restrict__ S) {
    int bh = blockIdx.x >> 5, ds = blockIdx.x & 31;   // 384 blocks
    int b = bh / HEADS, h = bh % HEADS;
    int tid = threadIdx.x;
    int wave = tid >> 6, lane = tid & 63;
    int quad = lane >> 4, l16 = lane & 15;
    int tm = wave >> 1, tn = wave & 1;
    const u16* qrow = qb_ + ((size_t)(b * 192 + h * 32 + tm * 16 + l16)) * HW + ds * 512 + quad * 8;
    const u16* krow = kb_ + ((size_t)(b * 384 + h * 32 + tn * 16 + l16)) * HW + ds * 512 + quad * 8;
    f32x4 acc = {};
#pragma unroll
    for (int ch = 0; ch < 16; ch++) {
        bf16x8 a = *(const bf16x8*)(qrow + ch * 32);
        bf16x8 k8 = *(const bf16x8*)(krow + ch * 32);
        acc = __builtin_amdgcn_mfma_f32_16x16x32_bf16(a, k8, acc, 0, 0, 0);
    }
    float* Sb = S + bh * 1024;
#pragma unroll
    for (int r = 0; r < 4; r++)
        atomicAdd(&Sb[(tm * 16 + quad * 4 + r) * 32 + tn * 16 + l16], acc[r]);
}

// ---------------- K5: softmax + fold attn into po weights: Weff = Wpo @ bd(A) -
__global__ __launch_bounds__(256) void k_smA(const float* __restrict__ S,
                                             const float* __restrict__ sqqp,
                                             const float* __restrict__ sqkp,
                                             const float* __restrict__ temp,
                                             const float* __restrict__ wpo,
                                             u16* __restrict__ weff) {
    __shared__ float A[32][33];
    __shared__ float scq[32], sck[32];
    int bh = blockIdx.x;
    int b = bh / HEADS, h = bh % HEADS;
    int t = threadIdx.x;
    if (t < 32) {
        const float* qp = sqqp + (b * 192 + h * 32 + t) * 4;
        const float* kp = sqkp + (b * 192 + h * 32 + t) * 4;
        scq[t] = 1.0f / fmaxf(sqrtf(qp[0] + qp[1] + qp[2] + qp[3]), 1e-12f);
        sck[t] = 1.0f / fmaxf(sqrtf(kp[0] + kp[1] + kp[2] + kp[3]), 1e-12f);
    }
    __syncthreads();
    float tmp = temp[h];
    for (int idx = t; idx < 1024; idx += 256) {
        int r = idx >> 5, e = idx & 31;
        A[r][e] = S[bh * 1024 + r * 32 + e] * scq[r] * sck[e] * tmp;
    }
    __syncthreads();
    if (t < 32) {
        float m = -1e30f;
        for (int e = 0; e < 32; e++) m = fmaxf(m, A[t][e]);
        float s = 0.f;
        for (int e = 0; e < 32; e++) { float ev = expf(A[t][e] - m); A[t][e] = ev; s += ev; }
        float inv = 1.0f / s;
        for (int e = 0; e < 32; e++) A[t][e] *= inv;
    }
    __syncthreads();
    for (int idx = t; idx < 6144; idx += 256) {
        int m = idx >> 5, e = idx & 31;
        float s = 0.f;
        const float* wr = wpo + m * 192 + h * 32;
#pragma unroll 8
        for (int c = 0; c < 32; c++) s += wr[c] * A[c][e];
        weff[((size_t)b * 192 + m) * 192 + h * 32 + e] = f2bf(s);
    }
}

// ---------------- K6: po GEMM (LDS): x1 = Weff@V + x; std layout + LN2 stats -
__global__ __launch_bounds__(256) void k_gemm_po(
    const u16* __restrict__ kvb, const u16* __restrict__ weff,
    const u16* __restrict__ residb, u16* __restrict__ x1b,
    float* __restrict__ sumP, float* __restrict__ sum2P) {
    __shared__ __align__(16) u16 Ws[64 * 32];
    __shared__ __align__(16) u16 Xs[32 * 130];
    const int tid = threadIdx.x;
    const int n0 = blockIdx.x * 128;
    const int m0 = blockIdx.y * 64;
    const int b = blockIdx.z;
    const u16* Xb = kvb + ((size_t)b * 384 + 192) * HW + n0;   // V rows
    const u16* Wb = weff + (size_t)b * 192 * 192;
    const int wave = tid >> 6, lane = tid & 63;
    const int quad = lane >> 4, l16 = lane & 15;
    const int smr = tid >> 2, sk4 = tid & 3;
    const int skr = tid >> 3, sc0 = (tid & 7) * 16;
    f32x4 acc[4][2] = {};
    for (int ch = 0; ch < 6; ch++) {
        const int k0 = ch * 32;
        if (ch) __syncthreads();
        {
            const int4 wv = *(const int4*)(Wb + (size_t)(m0 + smr) * 192 + k0 + sk4 * 8);
            *(int4*)&Ws[(smr << 5) + (((sk4 ^ (smr & 3)) & 3) << 3)] = wv;
        }
        {
            const u16* xc = Xb + (size_t)(k0 + skr) * HW + sc0;
            int4 r0 = *(const int4*)xc;
            int4 r1 = *(const int4*)(xc + 8);
            u32* dst = (u32*)&Xs[skr * 130 + sc0];
#pragma unroll
            for (int i = 0; i < 4; i++) dst[i] = ((const u32*)&r0)[i];
#pragma unroll
            for (int i = 0; i < 4; i++) dst[4 + i] = ((const u32*)&r1)[i];
        }
        __syncthreads();
        bf16x8 af[4];
#pragma unroll
        for (int mi = 0; mi < 4; mi++) {
            int row = mi * 16 + l16;
            af[mi] = *(const bf16x8*)&Ws[(row << 5) + ((quad ^ (row & 3)) << 3)];
        }
#pragma unroll
        for (int ni = 0; ni < 2; ni++) {
            int n = wave * 32 + ni * 16 + l16;
            bf16x8 bfr;
#pragma unroll
            for (int j = 0; j < 8; j++) bfr[j] = (short)Xs[(quad * 8 + j) * 130 + n];
#pragma unroll
            for (int mi = 0; mi < 4; mi++)
                acc[mi][ni] = __builtin_amdgcn_mfma_f32_16x16x32_bf16(af[mi], bfr, acc[mi][ni], 0, 0, 0);
        }
    }
    // epilogue: add bf16 x residual, write x1 std layout, LN2 stats partials
#pragma unroll
    for (int ni = 0; ni < 2; ni++) {
        int nl = wave * 32 + ni * 16 + l16;
        float s1 = 0.f, s2 = 0.f;
#pragma unroll
        for (int mi = 0; mi < 4; mi++)
#pragma unroll
            for (int r = 0; r < 4; r++) {
                int m = m0 + mi * 16 + quad * 4 + r;
                size_t idx = ((size_t)(b * 192 + m)) * HW + n0 + nl;
                float v = acc[mi][ni][r] + bf2f(residb[idx]);
                s1 += v; s2 += v * v;
                x1b[idx] = f2bf(v);
            }
        s1 += __shfl_xor(s1, 16, 64); s1 += __shfl_xor(s1, 32, 64);
        s2 += __shfl_xor(s2, 16, 64); s2 += __shfl_xor(s2, 32, 64);
        if (quad == 0) {
            sumP[((size_t)(b * 3 + blockIdx.y)) * HW + n0 + nl] = s1;
            sum2P[((size_t)(b * 3 + blockIdx.y)) * HW + n0 + nl] = s2;
        }
    }
}

// ---------------- K7: pin GEMM (LDS) over x1, folded-LN2 epilogue ------------
__global__ __launch_bounds__(256) void k_pin(
    const u16* __restrict__ X, const u16* __restrict__ wpb,
    const float* __restrict__ rsum, const float* __restrict__ biasp,
    const float* __restrict__ sumP, const float* __restrict__ sum2P,
    u16* __restrict__ out) {
    __shared__ __align__(16) u16 Ws[64 * 32];
    __shared__ __align__(16) u16 Xs[32 * 130];
    const int tid = threadIdx.x;
    const int n0 = blockIdx.x * 128;
    const int m0 = blockIdx.y * 64;
    const int b = blockIdx.z;
    const u16* Xb = X + (size_t)b * 192 * HW + n0;
    const u16* Wb = wpb + (size_t)b * 768 * 192;
    const int wave = tid >> 6, lane = tid & 63;
    const int quad = lane >> 4, l16 = lane & 15;
    const int smr = tid >> 2, sk4 = tid & 3;
    const int skr = tid >> 3, sc0 = (tid & 7) * 16;
    f32x4 acc[4][2] = {};
    for (int ch = 0; ch < 6; ch++) {
        const int k0 = ch * 32;
        if (ch) __syncthreads();
        {
            const int4 wv = *(const int4*)(Wb + (size_t)(m0 + smr) * 192 + k0 + sk4 * 8);
            *(int4*)&Ws[(smr << 5) + (((sk4 ^ (smr & 3)) & 3) << 3)] = wv;
        }
        {
            const u16* xc = Xb + (size_t)(k0 + skr) * HW + sc0;
            int4 r0 = *(const int4*)xc;
            int4 r1 = *(const int4*)(xc + 8);
            u32* dst = (u32*)&Xs[skr * 130 + sc0];
#pragma unroll
            for (int i = 0; i < 4; i++) dst[i] = ((const u32*)&r0)[i];
#pragma unroll
            for (int i = 0; i < 4; i++) dst[4 + i] = ((const u32*)&r1)[i];
        }
        __syncthreads();
        bf16x8 af[4];
#pragma unroll
        for (int mi = 0; mi < 4; mi++) {
            int row = mi * 16 + l16;
            af[mi] = *(const bf16x8*)&Ws[(row << 5) + ((quad ^ (row & 3)) << 3)];
        }
#pragma unroll
        for (int ni = 0; ni < 2; ni++) {
            int n = wave * 32 + ni * 16 + l16;
            bf16x8 bfr;
#pragma unroll
            for (int j = 0; j < 8; j++) bfr[j] = (short)Xs[(quad * 8 + j) * 130 + n];
#pragma unroll
            for (int mi = 0; mi < 4; mi++)
                acc[mi][ni] = __builtin_amdgcn_mfma_f32_16x16x32_bf16(af[mi], bfr, acc[mi][ni], 0, 0, 0);
        }
    }
    float rsv[4][4], biv[4][4];
#pragma unroll
    for (int mi = 0; mi < 4; mi++)
#pragma unroll
        for (int r = 0; r < 4; r++) {
            int m = m0 + mi * 16 + quad * 4 + r;
            rsv[mi][r] = rsum[b * 768 + m];
            biv[mi][r] = biasp[b * 768 + m];
        }
#pragma unroll
    for (int ni = 0; ni < 2; ni++) {
        int n = n0 + wave * 32 + ni * 16 + l16;
        size_t sb = (size_t)b * 3 * HW + n;
        float P = sumP[sb] + sumP[sb + HW] + sumP[sb + 2 * HW];
        float Q = sum2P[sb] + sum2P[sb + HW] + sum2P[sb + 2 * HW];
        float mu = P * (1.0f / 192.0f);
        float var = Q * (1.0f / 192.0f) - mu * mu;
        float rstd = rsqrtf(var + 1e-5f);
#pragma unroll
        for (int mi = 0; mi < 4; mi++)
#pragma unroll
            for (int r = 0; r < 4; r++) {
                int m = m0 + mi * 16 + quad * 4 + r;
                float v = rstd * (acc[mi][ni][r] - mu * rsv[mi][r]) + biv[mi][r];
                out[((size_t)(b * 768 + m)) * HW + n] = f2bf(v);
            }
    }
}

// ---------------- K8: depthwise 3x3 pair + exact GELU gate, LDS-tiled --------
__global__ __launch_bounds__(256) void k_dw_gelu2(const u16* __restrict__ G0,
                                                  const float* __restrict__ Wd,
                                                  u16* __restrict__ out) {
    __shared__ float In[2 * 34 * 132];
    int bc = blockIdx.x >> 2, rt = blockIdx.x & 3;
    int b = bc / 384, j = bc % 384;
    int t = threadIdx.x;
    int c0 = (t & 7) * 16;
    for (int pl = 0; pl < 2; pl++) {
        const u16* xb = G0 + ((size_t)b * 768 + pl * 384 + j) * HW;
        float* pla = &In[pl * 34 * 132];
        for (int r = t >> 3; r < 34; r += 32) {
            int y = rt * 32 - 1 + r;
            float* dst = &pla[r * 132 + 1 + c0];
            if ((unsigned)y < 128u) {
                const u16* src = xb + y * 128 + c0;
                int4 r0 = *(const int4*)src;
                int4 r1 = *(const int4*)(src + 8);
                const u16* p0 = (const u16*)&r0;
                const u16* p1 = (const u16*)&r1;
#pragma unroll
                for (int i = 0; i < 8; i++) dst[i] = bf2f(p0[i]);
#pragma unroll
                for (int i = 0; i < 8; i++) dst[8 + i] = bf2f(p1[i]);
            } else {
#pragma unroll
                for (int i = 0; i < 16; i++) dst[i] = 0.f;
            }
        }
        if (t < 34) { pla[t * 132] = 0.f; pla[t * 132 + 129] = 0.f; }
    }
    __syncthreads();
    const float* w1 = Wd + j * 9;
    const float* w2 = Wd + (384 + j) * 9;
    float a00 = w1[0], a01 = w1[1], a02 = w1[2], a10 = w1[3], a11 = w1[4],
          a12 = w1[5], a20 = w1[6], a21 = w1[7], a22 = w1[8];
    float b00 = w2[0], b01 = w2[1], b02 = w2[2], b10 = w2[3], b11 = w2[4],
          b12 = w2[5], b20 = w2[6], b21 = w2[7], b22 = w2[8];
    int x = t & 127, rg = t >> 7;
    int base = rg * 16;
    float A2a = 0.f, A1a = 0.f, B1a = 0.f;
    float A2b = 0.f, A1b = 0.f, B1b = 0.f;
    u16* ob = out + ((size_t)b * 384 + j) * HW + (rt * 32 + base) * 128 + x;
#pragma unroll
    for (int r = 0; r < 18; r++) {
        const float* r1p = &In[(base + r) * 132 + x];
        const float* r2p = r1p + 34 * 132;
        float u0 = r1p[0], u1 = r1p[1], u2 = r1p[2];
        float v0 = r2p[0], v1 = r2p[1], v2 = r2p[2];
        float h0a = a00 * u0 + a01 * u1 + a02 * u2;
        float h1a = a10 * u0 + a11 * u1 + a12 * u2;
        float h2a = a20 * u0 + a21 * u1 + a22 * u2;
        float h0b = b00 * v0 + b01 * v1 + b02 * v2;
        float h1b = b10 * v0 + b11 * v1 + b12 * v2;
        float h2b = b20 * v0 + b21 * v1 + b22 * v2;
        if (r >= 2) {
            float s1 = A2a + B1a + h2a;
            float s2 = A2b + B1b + h2b;
            float g = 0.5f * s1 * (1.0f + erff(s1 * 0.70710678118654752f));
            ob[(size_t)(r - 2) * 128] = f2bf(g * s2);
        }
        A2a = A1a; A1a = h0a; B1a = h1a;
        A2b = A1b; A1b = h0b; B1b = h1b;
    }
}

// ---------------- K9: pout GEMM (LDS), resid bf16 x1 std layout, fp32 out ----
__global__ __launch_bounds__(256) void k_gemm_pout(
    const u16* __restrict__ X, const u16* __restrict__ Wb,
    const u16* __restrict__ residb, float* __restrict__ out) {
    __shared__ __align__(16) u16 Ws[64 * 32];
    __shared__ __align__(16) u16 Xs[32 * 130];
    const int tid = threadIdx.x;
    const int n0 = blockIdx.x * 128;
    const int m0 = blockIdx.y * 64;
    const int b = blockIdx.z;
    const u16* Xb = X + (size_t)b * 384 * HW + n0;
    const int wave = tid >> 6, lane = tid & 63;
    const int quad = lane >> 4, l16 = lane & 15;
    const int smr = tid >> 2, sk4 = tid & 3;
    const int skr = tid >> 3, sc0 = (tid & 7) * 16;
    f32x4 acc[4][2] = {};
    for (int ch = 0; ch < 12; ch++) {
        const int k0 = ch * 32;
        if (ch) __syncthreads();
        {
            const int4 wv = *(const int4*)(Wb + (size_t)(m0 + smr) * 384 + k0 + sk4 * 8);
            *(int4*)&Ws[(smr << 5) + (((sk4 ^ (smr & 3)) & 3) << 3)] = wv;
        }
        {
            const u16* xc = Xb + (size_t)(k0 + skr) * HW + sc0;
            int4 r0 = *(const int4*)xc;
            int4 r1 = *(const int4*)(xc + 8);
            u32* dst = (u32*)&Xs[skr * 130 + sc0];
#pragma unroll
            for (int i = 0; i < 4; i++) dst[i] = ((const u32*)&r0)[i];
#pragma unroll
            for (int i = 0; i < 4; i++) dst[4 + i] = ((const u32*)&r1)[i];
        }
        __syncthreads();
        bf16x8 af[4];
#pragma unroll
        for (int mi = 0; mi < 4; mi++) {
            int row = mi * 16 + l16;
            af[mi] = *(const bf16x8*)&Ws[(row << 5) + ((quad ^ (row & 3)) << 3)];
        }
#pragma unroll
        for (int ni = 0; ni < 2; ni++) {
            int n = wave * 32 + ni * 16 + l16;
            bf16x8 bfr;
#pragma unroll
            for (int j = 0; j < 8; j++) bfr[j] = (short)Xs[(quad * 8 + j) * 130 + n];
#pragma unroll
            for (int mi = 0; mi < 4; mi++)
                acc[mi][ni] = __builtin_amdgcn_mfma_f32_16x16x32_bf16(af[mi], bfr, acc[mi][ni], 0, 0, 0);
        }
    }
#pragma unroll
    for (int mi = 0; mi < 4; mi++)
#pragma unroll
        for (int ni = 0; ni < 2; ni++)
#pragma unroll
            for (int r = 0; r < 4; r++) {
                int m = m0 + mi * 16 + quad * 4 + r;
                int n = n0 + wave * 32 + ni * 16 + l16;
                size_t idx = ((size_t)(b * 192 + m)) * HW + n;
                out[idx] = acc[mi][ni][r] + bf2f(residb[idx]);
            }
}

extern "C" void kernel_launch(void* const* d_in, const int* in_sizes, int n_in,
                              void* d_out, int out_size, void* d_ws, size_t ws_size,
                              hipStream_t stream) {
    const float* x     = (const float*)d_in[0];
    const float* k_v   = (const float*)d_in[1];
    const float* ln1w  = (const float*)d_in[2];
    const float* ln1b  = (const float*)d_in[3];
    const float* temp  = (const float*)d_in[4];
    const float* w_kR  = (const float*)d_in[5];
    const float* w_kI  = (const float*)d_in[6];
    const float* w_qR  = (const float*)d_in[7];
    const float* w_qdw = (const float*)d_in[8];
    const float* w_kvI = (const float*)d_in[9];
    const float* w_kvdw= (const float*)d_in[10];
    const float* w_po  = (const float*)d_in[11];
    const float* ln2w  = (const float*)d_in[12];
    const float* ln2b  = (const float*)d_in[13];
    const float* w_ffk = (const float*)d_in[14];
    const float* w_pin = (const float*)d_in[15];
    const float* w_dw  = (const float*)d_in[16];
    const float* w_pout= (const float*)d_in[17];
    float* out = (float*)d_out;

    const size_t MiB = 1048576ULL;
    u16*   xrb     = wsh(d_ws, 0);           // [2][144] bf16 (+overread slack into xib)
    u16*   xib     = wsh(d_ws, 10 * MiB);    // [2][48] bf16 (+overread slack)
    u16*   xb16    = wsh(d_ws, 14 * MiB);    // [2][192] raw x bf16
    u16*   q0b     = wsh(d_ws, 26 * MiB);    // [2][192] bf16
    u16*   kv0b    = wsh(d_ws, 38 * MiB);    // [2][384] bf16
    u16*   qbuf_b  = wsh(d_ws, 62 * MiB);    // [2][192] bf16
    u16*   kvbuf_b = wsh(d_ws, 74 * MiB);    // [2][384] bf16
    u16*   x1b     = wsh(d_ws, 98 * MiB);    // [2][192] bf16
    u16*   g0b     = wsh(d_ws, 110 * MiB);   // [2][768] bf16
    u16*   ybufb   = wsh(d_ws, 158 * MiB);   // [2][384] bf16
    u16*   wb      = wsh(d_ws, 182 * MiB);   // bf16 weights 627 KB
    u16*   weffb   = wsh(d_ws, 183 * MiB);   // [2][192][192] bf16
    u16*   wpinb   = wsh(d_ws, 184 * MiB);   // [2][768][192] bf16
    float* sm      = wsf(d_ws, 185 * MiB);   // smalls
    float* sumP    = wsf(d_ws, 186 * MiB);   // [2][3][HW]
    float* sum2P   = wsf(d_ws, 187 * MiB);   // [2][3][HW]
    u16* wq   = wb;            // [192][160]
    u16* wkv  = wb + 30720;    // [384][64]
    u16* wpout= wb + 239616;   // [192][384]
    float* kvr  = sm;               // 288
    float* kvi  = sm + 288;         // 96
    float* kvf  = sm + 384;         // 384
    float* sqqp = sm + 768;         // 1536
    float* sqkp = sm + 2304;        // 1536
    float* Smat = sm + 3840;        // 12288
    float* rsum = sm + 16128;       // 1536
    float* biasp= sm + 17664;       // 1536

    k_setup<<<1277, 256, 0, stream>>>(k_v, w_kR, w_kI, w_ffk, w_qR, w_kvI, w_po,
                                      w_pin, w_pout, wb, sm,
                                      out + (size_t)NB * CDIM * HW);
    k_setup2<<<6, 256, 0, stream>>>(w_pin, ln2w, ln2b, kvf, wpinb, rsum, biasp);
    k_ln1<<<NPX / 64, 256, 0, stream>>>(x, ln1w, ln1b, kvr, kvi, xrb, xib, xb16);
    k_gemm_qkv<<<dim3(128, 9, 2), 256, 0, stream>>>(xrb, xib, wq, wkv, q0b, kv0b);
    k_dw2m<<<4608, 256, 0, stream>>>(q0b, kv0b, w_qdw, w_kvdw, qbuf_b, kvbuf_b, sqqp, sqkp);
    k_qk<<<12 * 32, 256, 0, stream>>>(qbuf_b, kvbuf_b, Smat);
    k_smA<<<12, 256, 0, stream>>>(Smat, sqqp, sqkp, temp, w_po, weffb);
    k_gemm_po<<<dim3(128, 3, 2), 256, 0, stream>>>(kvbuf_b, weffb, xb16, x1b, sumP, sum2P);
    k_pin<<<dim3(128, 12, 2), 256, 0, stream>>>(x1b, wpinb, rsum, biasp, sumP, sum2P, g0b);
    k_dw_gelu2<<<NB * 384 * 4, 256, 0, stream>>>(g0b, w_dw, ybufb);
    k_gemm_pout<<<dim3(128, 3, 2), 256, 0, stream>>>(ybufb, wpout, x1b, out);
}